// Round 4
// baseline (221.787 us; speedup 1.0000x reference)
//
#include <hip/hip_runtime.h>
#include <hip/hip_bf16.h>
#include <stdint.h>

typedef __attribute__((ext_vector_type(8))) short bf16x8;
typedef __attribute__((ext_vector_type(4))) float f32x4;

__device__ __forceinline__ float blo(unsigned u){ union{float f;unsigned x;}v; v.x = u<<16; return v.f; }
__device__ __forceinline__ float bhi(unsigned u){ union{float f;unsigned x;}v; v.x = u & 0xFFFF0000u; return v.f; }
__device__ __forceinline__ unsigned short f2bf(float f){
  union{float f;unsigned x;}v; v.f=f; unsigned x=v.x;
  return (unsigned short)((x + 0x7fffu + ((x>>16)&1u)) >> 16);
}

// ---------------- ROI max-pool + token build (split over ph rows) ----------------
__global__ __launch_bounds__(256) void pool_kernel(
    const float* __restrict__ rois,
    const float* __restrict__ fm0, const float* __restrict__ fm1,
    const float* __restrict__ fm2, const float* __restrict__ fm3,
    float* __restrict__ pooled, unsigned short* __restrict__ tok)
{
  int n = blockIdx.x;        // 0..127 roi
  int ph = blockIdx.y;       // 0..6
  int c = threadIdx.x;       // 0..255 channel
  const float* r = rois + n*4;
  int b = n >> 6;            // batch
  float rx1=r[0], ry1=r[1], rx2=r[2], ry2=r[3];
  float size = sqrtf((rx2-rx1)*(ry2-ry1));
  int lvl = (int)(3.0f + logf(size/224.0f));
  if (lvl < 0) lvl = 0; if (lvl > 3) lvl = 3;
  const float strides_[4] = {4.f,8.f,16.f,32.f};
  const int hw_[4] = {160,80,40,20};
  float s = strides_[lvl]; int Hl = hw_[lvl];
  int x1 = (int)(rx1/s), y1 = (int)(ry1/s), x2 = (int)(rx2/s), y2 = (int)(ry2/s);
  #pragma unroll
  for (int it=0; it<7; ++it){
    bool need = (y2-y1+1) < 7;
    if (need){ y1 = (y1-1 > 0) ? y1-1 : 0; y2 = (y2+1 < Hl-1) ? y2+1 : Hl-1; }
  }
  #pragma unroll
  for (int it=0; it<7; ++it){
    bool need = (x2-x1+1) < 7;
    if (need){ x1 = (x1-1 > 0) ? x1-1 : 0; x2 = (x2+1 < Hl-1) ? x2+1 : Hl-1; }
  }
  int rh = y2-y1+1, rw = x2-x1+1;
  int kh = (rh+6)/7, sh = rh/7, kw = (rw+6)/7, sw = rw/7;
  const float* fm = (lvl==0)?fm0:(lvl==1)?fm1:(lvl==2)?fm2:fm3;
  const float* fp = fm + ((size_t)(b*256 + c))*(size_t)(Hl*Hl);
  int r0 = y1 + ph*sh;
  for (int pw=0; pw<7; ++pw){
    int c0 = x1 + pw*sw;
    float m = -3.4e38f;
    for (int i=0;i<kh;++i){
      const float* rp = fp + (size_t)(r0+i)*Hl + c0;
      for (int j=0;j<kw;++j) m = fmaxf(m, rp[j]);
    }
    int l = ph*7+pw;
    pooled[((size_t)n*256 + c)*49 + l] = m;
    tok[((size_t)n*49 + l)*256 + c] = f2bf(m);
  }
}

// ---------------- bf16 MFMA GEMM, B direct-from-global, B reg-double-buffered ----------------
// C[M, Nper*nmat] = A[M,K](bf16) * B[K,Nper] per matrix (f32 -> bf16 in-reg)
// A staged in LDS (double-buffered). B prefetched into registers one k-step
// ahead so its HBM latency hides under MFMA + barrier (loads stay in flight
// across s_barrier; only the consuming s_waitcnt vmcnt drains them).
// EPI 0: out_bf16 = val + bias   (per-matrix out pointer; used for fused QKV)
// EPI 1: O-proj: x[n, c*49+l] = val + bias + pooled[n,c,l]
// EPI 2: atomicAdd into outf (split-K), bias applied later
template<int EPI>
__global__ __launch_bounds__(256) void gemm_kernel(
    const unsigned short* __restrict__ A,
    const float* __restrict__ B0, const float* __restrict__ B1, const float* __restrict__ B2,
    const float* __restrict__ bias0, const float* __restrict__ bias1, const float* __restrict__ bias2,
    unsigned short* __restrict__ o0, unsigned short* __restrict__ o1, unsigned short* __restrict__ o2,
    float* __restrict__ outf, const float* __restrict__ pooled,
    int M, int Nper, int K, int nM, int nN, int kChunk)
{
  __shared__ __align__(16) unsigned short As[2][64][32];
  int per = nM*nN;
  int kc  = blockIdx.x / per;
  int rem = blockIdx.x - kc*per;
  int bm = rem % nM, bn = rem / nM;
  int m0 = bm*64, n0 = bn*64;
  int mat = n0 / Nper;
  int col0 = n0 - mat*Nper;
  const float* Bp    = (mat==0)?B0:(mat==1)?B1:B2;
  const float* biasp = (mat==0)?bias0:(mat==1)?bias1:bias2;
  unsigned short* outp = (mat==0)?o0:(mat==1)?o1:o2;
  int k0 = kc*kChunk, k1 = k0 + kChunk;
  int tid = threadIdx.x, lane = tid & 63, wave = tid >> 6;
  int wm = wave & 1, wn = wave >> 1;
  int rl = lane & 15, kidx = (lane>>4)<<3;

  f32x4 acc[2][2];
  #pragma unroll
  for (int i=0;i<2;++i)
    #pragma unroll
    for (int j=0;j<2;++j){ acc[i][j][0]=0.f; acc[i][j][1]=0.f; acc[i][j][2]=0.f; acc[i][j][3]=0.f; }

  int arow = tid >> 2, aseg = (tid & 3) << 3;
  const unsigned short* Ag = A + (size_t)(m0+arow)*K + aseg;
  const float* bcol = Bp + col0 + wn*32 + rl;

  // prologue: stage A[k0] into LDS, load B[k0] into regs
  uint4 av = *(const uint4*)(Ag + k0);
  *(uint4*)&As[0][arow][aseg] = av;
  float bcur0[8], bcur1[8];
  #pragma unroll
  for (int j=0;j<8;++j){
    size_t ro = (size_t)(k0 + kidx + j)*Nper;
    bcur0[j] = bcol[ro];
    bcur1[j] = bcol[ro + 16];
  }
  int buf = 0;
  for (int kk = k0; kk < k1; kk += 32){
    bool more = (kk + 32) < k1;
    float bnxt0[8], bnxt1[8];
    if (more){
      av = *(const uint4*)(Ag + kk + 32);
      #pragma unroll
      for (int j=0;j<8;++j){
        size_t ro = (size_t)(kk + 32 + kidx + j)*Nper;
        bnxt0[j] = bcol[ro];
        bnxt1[j] = bcol[ro + 16];
      }
    }
    __syncthreads();
    union { unsigned short s[8]; bf16x8 v; } ub0, ub1;
    #pragma unroll
    for (int j=0;j<8;++j){ ub0.s[j] = f2bf(bcur0[j]); ub1.s[j] = f2bf(bcur1[j]); }
    bf16x8 a0 = *(const bf16x8*)&As[buf][wm*32      + rl][kidx];
    bf16x8 a1 = *(const bf16x8*)&As[buf][wm*32 + 16 + rl][kidx];
    acc[0][0] = __builtin_amdgcn_mfma_f32_16x16x32_bf16(a0,ub0.v,acc[0][0],0,0,0);
    acc[0][1] = __builtin_amdgcn_mfma_f32_16x16x32_bf16(a0,ub1.v,acc[0][1],0,0,0);
    acc[1][0] = __builtin_amdgcn_mfma_f32_16x16x32_bf16(a1,ub0.v,acc[1][0],0,0,0);
    acc[1][1] = __builtin_amdgcn_mfma_f32_16x16x32_bf16(a1,ub1.v,acc[1][1],0,0,0);
    if (more){
      *(uint4*)&As[buf^1][arow][aseg] = av;
      #pragma unroll
      for (int j=0;j<8;++j){ bcur0[j]=bnxt0[j]; bcur1[j]=bnxt1[j]; }
    }
    buf ^= 1;
  }

  int rq = (lane>>4)<<2, cl = lane & 15;
  #pragma unroll
  for (int mr=0;mr<2;++mr){
    #pragma unroll
    for (int nc=0;nc<2;++nc){
      int rowb = m0 + wm*32 + mr*16 + rq;
      int colM = col0 + wn*32 + nc*16 + cl;
      #pragma unroll
      for (int r2=0;r2<4;++r2){
        float v = acc[mr][nc][r2];
        int rr = rowb + r2;
        if constexpr (EPI==0){
          v += biasp[colM];
          outp[(size_t)rr*Nper + colM] = f2bf(v);
        } else if constexpr (EPI==1){
          v += biasp[colM];
          int nn = rr/49, l = rr - nn*49;
          v += pooled[((size_t)nn*256 + colM)*49 + l];
          outp[(size_t)nn*12544 + colM*49 + l] = f2bf(v);
        } else {
          atomicAdd(&outf[(size_t)rr*Nper + colM], v);
        }
      }
    }
  }
}

// ---------------- per-ROI attention ----------------
__global__ __launch_bounds__(256) void attn_kernel(
    const unsigned short* __restrict__ Q, const unsigned short* __restrict__ Km,
    const unsigned short* __restrict__ V, unsigned short* __restrict__ ctx)
{
  int n = blockIdx.x, tid = threadIdx.x;
  __shared__ __align__(16) unsigned short qs[49*256];
  __shared__ __align__(16) unsigned short ks[49*256];
  __shared__ float S[49*49];
  const uint4* qg = (const uint4*)(Q + (size_t)n*49*256);
  const uint4* kg = (const uint4*)(Km + (size_t)n*49*256);
  uint4* qsl = (uint4*)qs; uint4* ksl = (uint4*)ks;
  for (int i = tid; i < 1568; i += 256){ qsl[i] = qg[i]; ksl[i] = kg[i]; }
  __syncthreads();
  for (int p = tid; p < 2401; p += 256){
    int i = p/49, j = p - i*49;
    const uint2* qr = (const uint2*)(qs + i*256);
    const uint2* kr = (const uint2*)(ks + j*256);
    float sum = 0.f;
    #pragma unroll 8
    for (int c4 = 0; c4 < 64; ++c4){
      uint2 qv = qr[c4], kv = kr[c4];
      sum += blo(qv.x)*blo(kv.x) + bhi(qv.x)*bhi(kv.x);
      sum += blo(qv.y)*blo(kv.y) + bhi(qv.y)*bhi(kv.y);
    }
    S[p] = sum * (1.0f/16.0f);
  }
  __syncthreads();
  if (tid < 49){
    float* row = S + tid*49;
    float mx = row[0];
    for (int j=1;j<49;++j) mx = fmaxf(mx,row[j]);
    float sm = 0.f;
    for (int j=0;j<49;++j){ float e = expf(row[j]-mx); row[j]=e; sm+=e; }
    float inv = 1.0f/sm;
    for (int j=0;j<49;++j) row[j] *= inv;
  }
  __syncthreads();
  const uint4* vg = (const uint4*)(V + (size_t)n*49*256);
  for (int i = tid; i < 1568; i += 256) qsl[i] = vg[i];   // reuse qs for V
  __syncthreads();
  for (int idx = tid; idx < 6272; idx += 256){
    int i = idx >> 7, cp = idx & 127;
    const float* att = S + i*49;
    float s0=0.f, s1=0.f;
    #pragma unroll 7
    for (int j=0;j<49;++j){
      unsigned v = *(const unsigned*)&qs[j*256 + (cp<<1)];
      float a = att[j];
      s0 += a*blo(v); s1 += a*bhi(v);
    }
    unsigned outw = (unsigned)f2bf(s0) | ((unsigned)f2bf(s1) << 16);
    *(unsigned*)&ctx[((size_t)n*49 + i)*256 + (cp<<1)] = outw;
  }
}

// ---------------- bias + relu epilogues ----------------
__global__ void bias_relu_to_bf16(const float* __restrict__ acc, const float* __restrict__ bias,
                                  unsigned short* __restrict__ out, int total, int N){
  int i = blockIdx.x*256 + threadIdx.x;
  if (i < total){
    float v = acc[i] + bias[i & (N-1)];
    out[i] = f2bf(v > 0.f ? v : 0.f);
  }
}
__global__ void bias_relu_to_f32(const float* __restrict__ acc, const float* __restrict__ bias,
                                 float* __restrict__ out, int total, int N){
  int i = blockIdx.x*256 + threadIdx.x;
  if (i < total){
    float v = acc[i] + bias[i & (N-1)];
    out[i] = v > 0.f ? v : 0.f;
  }
}

// ---------------- heads ----------------
__global__ __launch_bounds__(256) void pack_wT(
    const float* __restrict__ wreg, const float* __restrict__ wcls, float* __restrict__ wT)
{
  int c = blockIdx.x, tid = threadIdx.x;
  if (c < 84){
    for (int k = tid; k < 2048; k += 256) wT[(size_t)c*2048 + k] = wreg[(size_t)k*84 + c];
  } else {
    int cc = c - 84;
    for (int k = tid; k < 2048; k += 256) wT[(size_t)c*2048 + k] = wcls[(size_t)k*21 + cc];
  }
}

__global__ __launch_bounds__(256) void heads_dot(
    const float* __restrict__ h2, const float* __restrict__ wT,
    const float* __restrict__ breg, const float* __restrict__ bcls,
    float* __restrict__ out, float* __restrict__ logits)
{
  int gw = (blockIdx.x*256 + threadIdx.x) >> 6;
  int lane = threadIdx.x & 63;
  int m = gw / 105, c = gw - m*105;
  const float4* hp = (const float4*)(h2 + (size_t)m*2048);
  const float4* wp = (const float4*)(wT + (size_t)c*2048);
  float sum = 0.f;
  #pragma unroll
  for (int i=0;i<8;++i){
    float4 a = hp[i*64 + lane];
    float4 b = wp[i*64 + lane];
    sum += a.x*b.x + a.y*b.y + a.z*b.z + a.w*b.w;
  }
  #pragma unroll
  for (int off=32; off; off>>=1) sum += __shfl_down(sum, off, 64);
  if (lane == 0){
    if (c < 84) out[(size_t)m*84 + c] = sum + breg[c];
    else        logits[(size_t)m*21 + (c-84)] = sum + bcls[c-84];
  }
}

__global__ __launch_bounds__(128) void cls_softmax(
    const float* __restrict__ logits, float* __restrict__ out)
{
  int m = threadIdx.x;
  const float* lg = logits + (size_t)m*21;
  float mx = lg[0];
  #pragma unroll
  for (int j=1;j<21;++j) mx = fmaxf(mx, lg[j]);
  float sm = 0.f;
  float e[21];
  #pragma unroll
  for (int j=0;j<21;++j){ e[j] = expf(lg[j]-mx); sm += e[j]; }
  float inv = 1.0f/sm;
  #pragma unroll
  for (int j=0;j<21;++j) out[10752 + (size_t)m*21 + j] = e[j]*inv;
}

extern "C" void kernel_launch(void* const* d_in, const int* in_sizes, int n_in,
                              void* d_out, int out_size, void* d_ws, size_t ws_size,
                              hipStream_t stream)
{
  (void)in_sizes; (void)n_in; (void)out_size; (void)ws_size;
  const float* rois = (const float*)d_in[0];
  const float* fm0  = (const float*)d_in[1];
  const float* fm1  = (const float*)d_in[2];
  const float* fm2  = (const float*)d_in[3];
  const float* fm3  = (const float*)d_in[4];
  const float* wq   = (const float*)d_in[5];
  const float* bq   = (const float*)d_in[6];
  const float* wk   = (const float*)d_in[7];
  const float* bk   = (const float*)d_in[8];
  const float* wv   = (const float*)d_in[9];
  const float* bv   = (const float*)d_in[10];
  const float* wo   = (const float*)d_in[11];
  const float* bo   = (const float*)d_in[12];
  const float* w1   = (const float*)d_in[13];
  const float* b1   = (const float*)d_in[14];
  const float* w2   = (const float*)d_in[15];
  const float* b2   = (const float*)d_in[16];
  const float* wreg = (const float*)d_in[17];
  const float* breg = (const float*)d_in[18];
  const float* wcls = (const float*)d_in[19];
  const float* bcls = (const float*)d_in[20];
  float* out = (float*)d_out;

  char* ws = (char*)d_ws;
  float*          pooled = (float*)(ws + 0);
  unsigned short* tok    = (unsigned short*)(ws + 6422528);
  unsigned short* Qb     = (unsigned short*)(ws + 9633792);
  unsigned short* Kb     = (unsigned short*)(ws + 12845056);
  unsigned short* Vb     = (unsigned short*)(ws + 16056320);
  unsigned short* ctx    = (unsigned short*)(ws + 19267584);
  unsigned short* xb     = (unsigned short*)(ws + 22478848);
  float*          h1acc  = (float*)(ws + 25690112);
  unsigned short* h1     = (unsigned short*)(ws + 26738688);
  float*          h2acc  = (float*)(ws + 27262976);
  float*          h2f    = (float*)(ws + 28311552);
  float*          wT     = (float*)(ws + 29360128);
  float*          logits = (float*)(ws + 30220288);

  dim3 pgrid(128, 7);
  pool_kernel<<<pgrid,256,0,stream>>>(rois, fm0, fm1, fm2, fm3, pooled, tok);
  pack_wT<<<105,256,0,stream>>>(wreg, wcls, wT);

  // fused QKV: [6272,256] x 3x[256,256], nM=98, nN=12
  gemm_kernel<0><<<1176,256,0,stream>>>(tok, wq,wk,wv, bq,bk,bv, Qb,Kb,Vb,
                                        nullptr, nullptr, 6272,256,256, 98,12, 256);

  attn_kernel<<<128,256,0,stream>>>(Qb, Kb, Vb, ctx);

  // O projection + residual + transpose
  gemm_kernel<1><<<392,256,0,stream>>>(ctx, wo,wo,wo, bo,bo,bo, xb,xb,xb,
                                       nullptr, pooled, 6272,256,256, 98,4, 256);

  // fc1: [128,12544] x [12544,2048], split-K=28 -> 1792 blocks, kChunk=448
  hipMemsetAsync(h1acc, 0, 128*2048*sizeof(float), stream);
  gemm_kernel<2><<<1792,256,0,stream>>>(xb, w1,w1,w1, nullptr,nullptr,nullptr,
                                        nullptr,nullptr,nullptr, h1acc, nullptr,
                                        128,2048,12544, 2,32, 448);
  bias_relu_to_bf16<<<1024,256,0,stream>>>(h1acc, b1, h1, 128*2048, 2048);

  // fc2: [128,2048] x [2048,2048], split-K=16 -> 1024 blocks, kChunk=128
  hipMemsetAsync(h2acc, 0, 128*2048*sizeof(float), stream);
  gemm_kernel<2><<<1024,256,0,stream>>>(h1, w2,w2,w2, nullptr,nullptr,nullptr,
                                        nullptr,nullptr,nullptr, h2acc, nullptr,
                                        128,2048,2048, 2,32, 128);
  bias_relu_to_f32<<<1024,256,0,stream>>>(h2acc, b2, h2f, 128*2048, 2048);

  heads_dot<<<3360,256,0,stream>>>(h2f, wT, breg, bcls, out, logits);
  cls_softmax<<<1,128,0,stream>>>(logits, out);
}

// Round 5
// 187.205 us; speedup vs baseline: 1.1847x; 1.1847x over previous
//
#include <hip/hip_runtime.h>
#include <hip/hip_bf16.h>
#include <stdint.h>

typedef __attribute__((ext_vector_type(8))) short bf16x8;
typedef __attribute__((ext_vector_type(4))) float f32x4;

__device__ __forceinline__ float blo(unsigned u){ union{float f;unsigned x;}v; v.x = u<<16; return v.f; }
__device__ __forceinline__ float bhi(unsigned u){ union{float f;unsigned x;}v; v.x = u & 0xFFFF0000u; return v.f; }
__device__ __forceinline__ unsigned short f2bf(float f){
  union{float f;unsigned x;}v; v.f=f; unsigned x=v.x;
  return (unsigned short)((x + 0x7fffu + ((x>>16)&1u)) >> 16);
}
__device__ __forceinline__ float b2f(unsigned short h){ union{float f;unsigned x;}v; v.x = ((unsigned)h)<<16; return v.f; }

// ---------------- ROI max-pool + token build, fused with wT pack ----------------
__global__ __launch_bounds__(256) void pool_pack_kernel(
    const float* __restrict__ rois,
    const float* __restrict__ fm0, const float* __restrict__ fm1,
    const float* __restrict__ fm2, const float* __restrict__ fm3,
    float* __restrict__ pooled, unsigned short* __restrict__ tok,
    const float* __restrict__ wreg, const float* __restrict__ wcls, float* __restrict__ wT)
{
  int bx = blockIdx.x;
  int tid = threadIdx.x;
  if (bx >= 896){
    int c = bx - 896;   // 0..104
    if (c < 84){
      for (int k = tid; k < 2048; k += 256) wT[(size_t)c*2048 + k] = wreg[(size_t)k*84 + c];
    } else {
      int cc = c - 84;
      for (int k = tid; k < 2048; k += 256) wT[(size_t)c*2048 + k] = wcls[(size_t)k*21 + cc];
    }
    return;
  }
  int n = bx / 7;            // roi
  int ph = bx - n*7;         // 0..6
  int c = tid;               // channel
  const float* r = rois + n*4;
  int b = n >> 6;
  float rx1=r[0], ry1=r[1], rx2=r[2], ry2=r[3];
  float size = sqrtf((rx2-rx1)*(ry2-ry1));
  int lvl = (int)(3.0f + logf(size/224.0f));
  if (lvl < 0) lvl = 0; if (lvl > 3) lvl = 3;
  const float strides_[4] = {4.f,8.f,16.f,32.f};
  const int hw_[4] = {160,80,40,20};
  float s = strides_[lvl]; int Hl = hw_[lvl];
  int x1 = (int)(rx1/s), y1 = (int)(ry1/s), x2 = (int)(rx2/s), y2 = (int)(ry2/s);
  #pragma unroll
  for (int it=0; it<7; ++it){
    bool need = (y2-y1+1) < 7;
    if (need){ y1 = (y1-1 > 0) ? y1-1 : 0; y2 = (y2+1 < Hl-1) ? y2+1 : Hl-1; }
  }
  #pragma unroll
  for (int it=0; it<7; ++it){
    bool need = (x2-x1+1) < 7;
    if (need){ x1 = (x1-1 > 0) ? x1-1 : 0; x2 = (x2+1 < Hl-1) ? x2+1 : Hl-1; }
  }
  int rh = y2-y1+1, rw = x2-x1+1;
  int kh = (rh+6)/7, sh = rh/7, kw = (rw+6)/7, sw = rw/7;
  const float* fm = (lvl==0)?fm0:(lvl==1)?fm1:(lvl==2)?fm2:fm3;
  const float* fp = fm + ((size_t)(b*256 + c))*(size_t)(Hl*Hl);
  int r0 = y1 + ph*sh;
  for (int pw=0; pw<7; ++pw){
    int c0 = x1 + pw*sw;
    float m = -3.4e38f;
    for (int i=0;i<kh;++i){
      const float* rp = fp + (size_t)(r0+i)*Hl + c0;
      for (int j=0;j<kw;++j) m = fmaxf(m, rp[j]);
    }
    int l = ph*7+pw;
    pooled[((size_t)n*256 + c)*49 + l] = m;
    tok[((size_t)n*49 + l)*256 + c] = f2bf(m);
  }
}

// ---------------- bf16 MFMA GEMM: vectorized B->LDS staging, swizzled frag reads ----------------
// C[M, Nper*nmat] = A[M,K] * B[K,Nper]; B f32 staged to LDS as bf16.
// Bs layout (per buf): short idx = k*64 + (n ^ ((k>>3)<<4)), k in 0..31, n in 0..63.
//   write: thread t -> k=t>>3, n=(t&7)*8..+7 -> one b128, slots conflict-free.
//   read:  lane (g=lane>>4, c=lane&15), frag elem j: idx=(g*8+j)*64 + ((nb^g)*16+c)
//          -> banks ((nb^g)*8 + (c>>1)) span all 32 -> conflict-free u16 reads.
// ASRC 0: A bf16; ASRC 1: A f32 + biasA + relu (fuses fc1's epilogue into fc2)
// EPI 0: out = val + bias (per-matrix ptr, fused QKV)
// EPI 1: O-proj: x[n, c*49+l] = val + bias + pooled; EPI 2: atomicAdd split-K
template<int EPI, int ASRC>
__global__ __launch_bounds__(256) void gemm_kernel(
    const unsigned short* __restrict__ A, const float* __restrict__ Af,
    const float* __restrict__ biasA,
    const float* __restrict__ B0, const float* __restrict__ B1, const float* __restrict__ B2,
    const float* __restrict__ bias0, const float* __restrict__ bias1, const float* __restrict__ bias2,
    unsigned short* __restrict__ o0, unsigned short* __restrict__ o1, unsigned short* __restrict__ o2,
    float* __restrict__ outf, const float* __restrict__ pooled,
    int M, int Nper, int K, int nM, int nN, int kChunk)
{
  __shared__ __align__(16) unsigned short As[2][64][32];
  __shared__ __align__(16) unsigned short Bs[2][2048];
  int per = nM*nN;
  int kc  = blockIdx.x / per;
  int rem = blockIdx.x - kc*per;
  int bm = rem % nM, bn = rem / nM;
  int m0 = bm*64, n0 = bn*64;
  int mat = n0 / Nper;
  int col0 = n0 - mat*Nper;
  const float* Bp    = (mat==0)?B0:(mat==1)?B1:B2;
  const float* biasp = (mat==0)?bias0:(mat==1)?bias1:bias2;
  unsigned short* outp = (mat==0)?o0:(mat==1)?o1:o2;
  int k0 = kc*kChunk, k1 = k0 + kChunk;
  int tid = threadIdx.x, lane = tid & 63, wave = tid >> 6;
  int wm = wave & 1, wn = wave >> 1;
  int g = lane >> 4, c = lane & 15;
  int kidx = g << 3;

  f32x4 acc[2][2];
  #pragma unroll
  for (int i=0;i<2;++i)
    #pragma unroll
    for (int j=0;j<2;++j){ acc[i][j][0]=0.f; acc[i][j][1]=0.f; acc[i][j][2]=0.f; acc[i][j][3]=0.f; }

  // A staging ids
  int arow = tid >> 2, aseg = (tid & 3) << 3;
  const unsigned short* Ag = (ASRC==0) ? (A + (size_t)(m0+arow)*K + aseg) : nullptr;
  const float* Ag32 = (ASRC==1) ? (Af + (size_t)(m0+arow)*K + aseg) : nullptr;
  // B staging ids
  int brow = tid >> 3;          // k-row 0..31
  int bcg  = tid & 7;           // 8-col group
  int bw_idx = brow*64 + ((bcg*8) ^ ((brow>>3)<<4));
  // frag read bases
  int nb0 = wn*2, nb1 = wn*2 + 1;
  int rb0 = g*512 + ((nb0^g)*16 + c);
  int rb1 = g*512 + ((nb1^g)*16 + c);

  uint4 av; float4 af0, af1, ba0, ba1, bv0, bv1;
  auto loadA = [&](int kk){
    if (ASRC==0){ av = *(const uint4*)(Ag + kk); }
    else {
      af0 = *(const float4*)(Ag32 + kk); af1 = *(const float4*)(Ag32 + kk + 4);
      ba0 = *(const float4*)(biasA + kk + aseg); ba1 = *(const float4*)(biasA + kk + aseg + 4);
    }
  };
  auto loadB = [&](int kk){
    const float* p = Bp + (size_t)(kk + brow)*Nper + col0 + bcg*8;
    bv0 = *(const float4*)p; bv1 = *(const float4*)(p+4);
  };
  auto writeA = [&](int b){
    if (ASRC==0){ *(uint4*)&As[b][arow][aseg] = av; }
    else {
      union { unsigned short s[8]; uint4 u; } w;
      float t0 = fmaxf(af0.x+ba0.x,0.f), t1 = fmaxf(af0.y+ba0.y,0.f);
      float t2 = fmaxf(af0.z+ba0.z,0.f), t3 = fmaxf(af0.w+ba0.w,0.f);
      float t4 = fmaxf(af1.x+ba1.x,0.f), t5 = fmaxf(af1.y+ba1.y,0.f);
      float t6 = fmaxf(af1.z+ba1.z,0.f), t7 = fmaxf(af1.w+ba1.w,0.f);
      w.s[0]=f2bf(t0); w.s[1]=f2bf(t1); w.s[2]=f2bf(t2); w.s[3]=f2bf(t3);
      w.s[4]=f2bf(t4); w.s[5]=f2bf(t5); w.s[6]=f2bf(t6); w.s[7]=f2bf(t7);
      *(uint4*)&As[b][arow][aseg] = w.u;
    }
  };
  auto writeB = [&](int b){
    union { unsigned short s[8]; uint4 u; } w;
    w.s[0]=f2bf(bv0.x); w.s[1]=f2bf(bv0.y); w.s[2]=f2bf(bv0.z); w.s[3]=f2bf(bv0.w);
    w.s[4]=f2bf(bv1.x); w.s[5]=f2bf(bv1.y); w.s[6]=f2bf(bv1.z); w.s[7]=f2bf(bv1.w);
    *(uint4*)&Bs[b][bw_idx] = w.u;
  };

  loadA(k0); loadB(k0);
  writeA(0); writeB(0);
  int buf = 0;
  for (int kk = k0; kk < k1; kk += 32){
    bool more = (kk + 32) < k1;
    if (more){ loadA(kk+32); loadB(kk+32); }
    __syncthreads();
    union { unsigned short s[8]; bf16x8 v; } ub0, ub1;
    const unsigned short* bsp = &Bs[buf][0];
    #pragma unroll
    for (int j=0;j<8;++j){ ub0.s[j] = bsp[rb0 + j*64]; ub1.s[j] = bsp[rb1 + j*64]; }
    bf16x8 a0 = *(const bf16x8*)&As[buf][wm*32      + c][kidx];
    bf16x8 a1 = *(const bf16x8*)&As[buf][wm*32 + 16 + c][kidx];
    acc[0][0] = __builtin_amdgcn_mfma_f32_16x16x32_bf16(a0,ub0.v,acc[0][0],0,0,0);
    acc[0][1] = __builtin_amdgcn_mfma_f32_16x16x32_bf16(a0,ub1.v,acc[0][1],0,0,0);
    acc[1][0] = __builtin_amdgcn_mfma_f32_16x16x32_bf16(a1,ub0.v,acc[1][0],0,0,0);
    acc[1][1] = __builtin_amdgcn_mfma_f32_16x16x32_bf16(a1,ub1.v,acc[1][1],0,0,0);
    if (more){ writeA(buf^1); writeB(buf^1); }
    buf ^= 1;
  }

  int rq = g << 2, cl = c;
  #pragma unroll
  for (int mr=0;mr<2;++mr){
    #pragma unroll
    for (int nc=0;nc<2;++nc){
      int rowb = m0 + wm*32 + mr*16 + rq;
      int colM = col0 + wn*32 + nc*16 + cl;
      #pragma unroll
      for (int r2=0;r2<4;++r2){
        float v = acc[mr][nc][r2];
        int rr = rowb + r2;
        if constexpr (EPI==0){
          v += biasp[colM];
          outp[(size_t)rr*Nper + colM] = f2bf(v);
        } else if constexpr (EPI==1){
          v += biasp[colM];
          int nn = rr/49, l = rr - nn*49;
          v += pooled[((size_t)nn*256 + colM)*49 + l];
          outp[(size_t)nn*12544 + colM*49 + l] = f2bf(v);
        } else {
          atomicAdd(&outf[(size_t)rr*Nper + colM], v);
        }
      }
    }
  }
}

// ---------------- per-ROI attention: 2 blocks/roi, padded K/V rows (bank-conflict fix) ----------------
__global__ __launch_bounds__(256) void attn_kernel(
    const unsigned short* __restrict__ Q, const unsigned short* __restrict__ Km,
    const unsigned short* __restrict__ V, unsigned short* __restrict__ ctx)
{
  int n = blockIdx.x, half = blockIdx.y, tid = threadIdx.x;
  int r0 = half*25, rcnt = half ? 24 : 25;
  __shared__ __align__(16) unsigned short qs[25*256];
  __shared__ __align__(16) unsigned short ks[49*260];   // padded rows: stride 260 shorts
  __shared__ float S[25*49];
  const uint4* qg = (const uint4*)(Q + ((size_t)n*49 + r0)*256);
  for (int i = tid; i < rcnt*32; i += 256) ((uint4*)qs)[i] = qg[i];
  const uint2* kg = (const uint2*)(Km + (size_t)n*49*256);
  for (int i = tid; i < 49*64; i += 256){
    int j = i >> 6, s = i & 63;
    *(uint2*)(ks + j*260 + s*4) = kg[i];
  }
  __syncthreads();
  for (int p = tid; p < rcnt*49; p += 256){
    int i = p/49, j = p - i*49;
    const uint2* qr = (const uint2*)(qs + i*256);
    const uint2* kr = (const uint2*)(ks + j*260);
    float sum = 0.f;
    #pragma unroll 8
    for (int c4 = 0; c4 < 64; ++c4){
      uint2 qv = qr[c4], kv = kr[c4];
      sum += blo(qv.x)*blo(kv.x) + bhi(qv.x)*bhi(kv.x);
      sum += blo(qv.y)*blo(kv.y) + bhi(qv.y)*bhi(kv.y);
    }
    S[p] = sum * (1.0f/16.0f);
  }
  __syncthreads();
  // V overwrites ks (same padded layout); softmax runs on first 25 lanes meanwhile
  const uint2* vg = (const uint2*)(V + (size_t)n*49*256);
  for (int i = tid; i < 49*64; i += 256){
    int j = i >> 6, s = i & 63;
    *(uint2*)(ks + j*260 + s*4) = vg[i];
  }
  if (tid < rcnt){
    float* row = S + tid*49;
    float mx = row[0];
    for (int j=1;j<49;++j) mx = fmaxf(mx,row[j]);
    float sm = 0.f;
    for (int j=0;j<49;++j){ float e = expf(row[j]-mx); row[j]=e; sm+=e; }
    float inv = 1.0f/sm;
    for (int j=0;j<49;++j) row[j] *= inv;
  }
  __syncthreads();
  for (int idx = tid; idx < rcnt*64; idx += 256){
    int i = idx >> 6, cp4 = idx & 63;
    const float* att = S + i*49;
    float s0=0.f, s1=0.f, s2=0.f, s3=0.f;
    #pragma unroll 7
    for (int j=0;j<49;++j){
      uint2 v = *(const uint2*)(ks + j*260 + cp4*4);
      float a = att[j];
      s0 += a*blo(v.x); s1 += a*bhi(v.x);
      s2 += a*blo(v.y); s3 += a*bhi(v.y);
    }
    uint2 outw;
    outw.x = (unsigned)f2bf(s0) | ((unsigned)f2bf(s1) << 16);
    outw.y = (unsigned)f2bf(s2) | ((unsigned)f2bf(s3) << 16);
    *(uint2*)&ctx[((size_t)n*49 + r0 + i)*256 + cp4*4] = outw;
  }
}

// ---------------- heads: fused bias+relu on h2acc ----------------
__global__ __launch_bounds__(256) void heads_dot(
    const float* __restrict__ h2acc, const float* __restrict__ b2,
    const float* __restrict__ wT,
    const float* __restrict__ breg, const float* __restrict__ bcls,
    float* __restrict__ out, float* __restrict__ logits)
{
  int gw = (blockIdx.x*256 + threadIdx.x) >> 6;
  int lane = threadIdx.x & 63;
  int m = gw / 105, c = gw - m*105;
  const float4* hp = (const float4*)(h2acc + (size_t)m*2048);
  const float4* bp = (const float4*)b2;
  const float4* wp = (const float4*)(wT + (size_t)c*2048);
  float sum = 0.f;
  #pragma unroll
  for (int i=0;i<8;++i){
    float4 a = hp[i*64 + lane];
    float4 bb = bp[i*64 + lane];
    float4 w = wp[i*64 + lane];
    sum += fmaxf(a.x+bb.x,0.f)*w.x + fmaxf(a.y+bb.y,0.f)*w.y
         + fmaxf(a.z+bb.z,0.f)*w.z + fmaxf(a.w+bb.w,0.f)*w.w;
  }
  #pragma unroll
  for (int off=32; off; off>>=1) sum += __shfl_down(sum, off, 64);
  if (lane == 0){
    if (c < 84) out[(size_t)m*84 + c] = sum + breg[c];
    else        logits[(size_t)m*21 + (c-84)] = sum + bcls[c-84];
  }
}

__global__ __launch_bounds__(128) void cls_softmax(
    const float* __restrict__ logits, float* __restrict__ out)
{
  int m = threadIdx.x;
  const float* lg = logits + (size_t)m*21;
  float mx = lg[0];
  #pragma unroll
  for (int j=1;j<21;++j) mx = fmaxf(mx, lg[j]);
  float sm = 0.f;
  float e[21];
  #pragma unroll
  for (int j=0;j<21;++j){ e[j] = expf(lg[j]-mx); sm += e[j]; }
  float inv = 1.0f/sm;
  #pragma unroll
  for (int j=0;j<21;++j) out[10752 + (size_t)m*21 + j] = e[j]*inv;
}

extern "C" void kernel_launch(void* const* d_in, const int* in_sizes, int n_in,
                              void* d_out, int out_size, void* d_ws, size_t ws_size,
                              hipStream_t stream)
{
  (void)in_sizes; (void)n_in; (void)out_size; (void)ws_size;
  const float* rois = (const float*)d_in[0];
  const float* fm0  = (const float*)d_in[1];
  const float* fm1  = (const float*)d_in[2];
  const float* fm2  = (const float*)d_in[3];
  const float* fm3  = (const float*)d_in[4];
  const float* wq   = (const float*)d_in[5];
  const float* bq   = (const float*)d_in[6];
  const float* wk   = (const float*)d_in[7];
  const float* bk   = (const float*)d_in[8];
  const float* wv   = (const float*)d_in[9];
  const float* bv   = (const float*)d_in[10];
  const float* wo   = (const float*)d_in[11];
  const float* bo   = (const float*)d_in[12];
  const float* w1   = (const float*)d_in[13];
  const float* b1   = (const float*)d_in[14];
  const float* w2   = (const float*)d_in[15];
  const float* b2   = (const float*)d_in[16];
  const float* wreg = (const float*)d_in[17];
  const float* breg = (const float*)d_in[18];
  const float* wcls = (const float*)d_in[19];
  const float* bcls = (const float*)d_in[20];
  float* out = (float*)d_out;

  char* ws = (char*)d_ws;
  float*          pooled = (float*)(ws + 0);                  // 6,422,528
  unsigned short* tok    = (unsigned short*)(ws + 6422528);   // 3,211,264
  unsigned short* Qb     = (unsigned short*)(ws + 9633792);
  unsigned short* Kb     = (unsigned short*)(ws + 12845056);
  unsigned short* Vb     = (unsigned short*)(ws + 16056320);
  unsigned short* ctx    = (unsigned short*)(ws + 19267584);
  unsigned short* xb     = (unsigned short*)(ws + 22478848);  // 128*12544 bf16
  float*          h1acc  = (float*)(ws + 25690112);           // 1 MB
  float*          h2acc  = (float*)(ws + 26738688);           // 1 MB (adjacent -> one memset)
  float*          wT     = (float*)(ws + 27787264);           // 860,160
  float*          logits = (float*)(ws + 28647424);           // 10,752

  hipMemsetAsync(h1acc, 0, 2097152, stream);   // zeroes h1acc + h2acc

  pool_pack_kernel<<<1001,256,0,stream>>>(rois, fm0, fm1, fm2, fm3, pooled, tok, wreg, wcls, wT);

  // fused QKV: [6272,256] x 3x[256,256]
  gemm_kernel<0,0><<<1176,256,0,stream>>>(tok, nullptr, nullptr, wq,wk,wv, bq,bk,bv,
                                          Qb,Kb,Vb, nullptr, nullptr, 6272,256,256, 98,12, 256);

  attn_kernel<<<dim3(128,2),256,0,stream>>>(Qb, Kb, Vb, ctx);

  // O projection + residual + transpose
  gemm_kernel<1,0><<<392,256,0,stream>>>(ctx, nullptr, nullptr, wo,wo,wo, bo,bo,bo,
                                         xb,xb,xb, nullptr, pooled, 6272,256,256, 98,4, 256);

  // fc1: [128,12544]x[12544,2048], split-K=28 -> 1792 blocks
  gemm_kernel<2,0><<<1792,256,0,stream>>>(xb, nullptr, nullptr, w1,w1,w1,
                                          nullptr,nullptr,nullptr, nullptr,nullptr,nullptr,
                                          h1acc, nullptr, 128,2048,12544, 2,32, 448);

  // fc2: [128,2048]x[2048,2048], split-K=16 -> 1024 blocks; A = relu(h1acc + b1) fused
  gemm_kernel<2,1><<<1024,256,0,stream>>>(nullptr, h1acc, b1, w2,w2,w2,
                                          nullptr,nullptr,nullptr, nullptr,nullptr,nullptr,
                                          h2acc, nullptr, 128,2048,2048, 2,32, 128);

  // heads: bias+relu on h2acc fused into the dot
  heads_dot<<<3360,256,0,stream>>>(h2acc, b2, wT, breg, bcls, out, logits);
  cls_softmax<<<1,128,0,stream>>>(logits, out);
}